// Round 8
// baseline (112.531 us; speedup 1.0000x reference)
//
#include <hip/hip_runtime.h>

typedef __attribute__((ext_vector_type(8))) _Float16 f16x8;
typedef __attribute__((ext_vector_type(4))) float    f32x4;
typedef __attribute__((ext_vector_type(4))) int      i32x4;

#define SLOPE 0.2f

// f32 -> f16 RNE (default rounding of the cast), packed pair as one dword
__device__ __forceinline__ int pk2(float lo, float hi) {
    _Float16 a = (_Float16)lo, b = (_Float16)hi;
    unsigned short ua = __builtin_bit_cast(unsigned short, a);
    unsigned short ub = __builtin_bit_cast(unsigned short, b);
    return (int)((unsigned)ua | ((unsigned)ub << 16));
}

__device__ __forceinline__ f32x4 lrelu4(f32x4 v) {
    return __builtin_elementwise_max(v, SLOPE * v);
}
__device__ __forceinline__ float fast_tanh(float v) {
    float e = __expf(2.0f * v);
    return 1.0f - 2.0f * __builtin_amdgcn_rcpf(e + 1.0f);
}

// Feature-axis exchange: D-layout rows (row=q*4+reg over two frags) ->
// next-layer B-layout (lane q holds k=8q..8q+7), same column n. Pure
// cross-lane ds_bpermute within the wave: no LDS memory, no barrier.
// Source lane (n,sq) packs: P0=rows(4sq,4sq+1) P1=(4sq+2,4sq+3)
// P2=(16+4sq,16+4sq+1) P3=(16+4sq+2,16+4sq+3). Target (n,q) dword d holds
// rows (8q+2d, 8q+2d+1). All bpermutes run under full EXEC; select after.
// (Mapping numerically verified in R7: its only failure was bf16 roundoff.)
__device__ __forceinline__ f16x8 xchg(f32x4 lo, f32x4 hi, int a01, int a23,
                                      bool hiq) {
    int P0 = pk2(lo.x, lo.y), P1 = pk2(lo.z, lo.w);
    int P2 = pk2(hi.x, hi.y), P3 = pk2(hi.z, hi.w);
    int e0 = __builtin_amdgcn_ds_bpermute(a01, P0);
    int f0 = __builtin_amdgcn_ds_bpermute(a01, P2);
    int e1 = __builtin_amdgcn_ds_bpermute(a01, P1);
    int f1 = __builtin_amdgcn_ds_bpermute(a01, P3);
    int e2 = __builtin_amdgcn_ds_bpermute(a23, P0);
    int f2 = __builtin_amdgcn_ds_bpermute(a23, P2);
    int e3 = __builtin_amdgcn_ds_bpermute(a23, P1);
    int f3 = __builtin_amdgcn_ds_bpermute(a23, P3);
    i32x4 r = { hiq ? f0 : e0, hiq ? f1 : e1, hiq ? f2 : e2, hiq ? f3 : e3 };
    return __builtin_bit_cast(f16x8, r);
}

// MFMA formulation (R7 structure, fp16 inputs for 8x less roundoff than
// bf16): per 16-sample group each conv layer is one K=32 GEMM
// D[m=feature][n=sample] = A_banded[m][k] * B_act[k][n] + bias, as two
// 16x16x32 f16 MFMAs (M=32 split in halves). Upsampling folded into banded
// A of conv3/conv4. Feature flattening chosen so each layer's D-row index
// == next layer's B-k index, so transitions are the pure-VALU xchg above.
// Weights+biases hoisted into fragments -> no scalar loads in steady loop.
__global__ __launch_bounds__(256, 4) void minigen_kernel(
    const float* __restrict__ x,
    const float* __restrict__ w1, const float* __restrict__ b1,
    const float* __restrict__ w2, const float* __restrict__ b2,
    const float* __restrict__ w3, const float* __restrict__ b3,
    const float* __restrict__ w4, const float* __restrict__ b4,
    float* __restrict__ out)
{
    __shared__ __align__(16) float sdata[256 * 36];     // 256 samples x 32 + pad
    __shared__ __align__(16) _Float16 atab[4][32 * 32]; // banded A, f16
    __shared__ __align__(16) float btab[4][32];         // bias per row

    const int t = threadIdx.x;
    const int lane = t & 63;
    const int w = t >> 6;                 // wave index 0..3
    const int n = lane & 15, q = lane >> 4;
    const int blockBase = blockIdx.x * 2048;  // float4 units

    // ---- build banded weight tables: wave w builds layer w ----
    {
        const int L = w;
#pragma unroll
        for (int i = 0; i < 16; ++i) {
            int idx = (lane << 4) + i;            // 1024 entries per layer
            int m = idx >> 5, k = idx & 31;
            float v = 0.0f;
            if (L == 0) {            // m=(oc4,l8), k=(ic2,j16)
                int oc = m >> 3, l = m & 7, ic = k >> 4, j = k & 15;
                int t3 = j - 2 * l + 1;
                if (t3 >= 0 && t3 < 3) v = w1[(oc * 2 + ic) * 3 + t3];
            } else if (L == 1) {     // m=(oc8,l4), k=(ic4,j8)
                int oc = m >> 2, l = m & 3, ic = k >> 3, j = k & 7;
                int t3 = j - 2 * l + 1;
                if (t3 >= 0 && t3 < 3) v = w2[(oc * 4 + ic) * 3 + t3];
            } else if (L == 2) {     // m=(oc4,l8), k=(ic8,j4), up1 folded
                int oc = m >> 3, l = m & 7, ic = k >> 2, j = k & 3;
                for (int t3 = 0; t3 < 3; ++t3) {
                    int u = l - 1 + t3;
                    if (u >= 0 && u < 8 && (u >> 1) == j)
                        v += w3[(oc * 8 + ic) * 3 + t3];
                }
            } else {                 // m=(oc2,l16), k=(ic4,j8), up2 folded
                int oc = m >> 4, l = m & 15, ic = k >> 3, j = k & 7;
                for (int t3 = 0; t3 < 3; ++t3) {
                    int u = l - 1 + t3;
                    if (u >= 0 && u < 16 && (u >> 1) == j)
                        v += w4[(oc * 4 + ic) * 3 + t3];
                }
            }
            atab[L][(m << 5) + k] = (_Float16)v;   // RNE
        }
    }
    if (t < 128) {                   // bias expanded to per-row
        int L = t >> 5, m = t & 31;
        float b;
        if (L == 0)      b = b1[m >> 3];
        else if (L == 1) b = b2[m >> 2];
        else if (L == 2) b = b3[m >> 3];
        else             b = b4[m >> 4];
        btab[L][m] = b;
    }

    // ---- stage in: coalesced global -> LDS ----
    const float4* xin = (const float4*)x;
    float4* s4 = (float4*)sdata;
#pragma unroll
    for (int qq = 0; qq < 8; ++qq) {
        int g = qq * 256 + t;
        s4[(g >> 3) * 9 + (g & 7)] = xin[blockBase + g];
    }
    __syncthreads();

    // ---- hoist A-fragments (A[m=lane&15][k=q*8+j]) and bias C-inits ----
    f16x8 A[4][2];
    f32x4 CB[4][2];
#pragma unroll
    for (int L = 0; L < 4; ++L)
#pragma unroll
        for (int h = 0; h < 2; ++h) {
            A[L][h]  = *(const f16x8*)&atab[L][(n + 16 * h) * 32 + q * 8];
            CB[L][h] = *(const f32x4*)&btab[L][16 * h + q * 4];
        }

    // bpermute source-lane addresses (bytes = lane*4)
    const int q2  = (q < 2) ? q : q - 2;
    const int a01 = (n + 32 * q2) * 4;
    const int a23 = a01 + 64;
    const bool hiq = (q >= 2);

    // ---- 4 groups of 16 samples per wave ----
#pragma unroll
    for (int g = 0; g < 4; ++g) {
        float* xrow = sdata + (w * 64 + g * 16 + n) * 36;

        // conv1 B-frag: this lane's k=8q..8q+7 words of sample n, f32->f16
        f32x4 xa = *(const f32x4*)(xrow + 8 * q);
        f32x4 xb = *(const f32x4*)(xrow + 8 * q + 4);
        i32x4 bi = { pk2(xa.x, xa.y), pk2(xa.z, xa.w),
                     pk2(xb.x, xb.y), pk2(xb.z, xb.w) };
        f16x8 B = __builtin_bit_cast(f16x8, bi);

        // conv1
        f32x4 d0 = __builtin_amdgcn_mfma_f32_16x16x32_f16(A[0][0], B, CB[0][0], 0, 0, 0);
        f32x4 d1 = __builtin_amdgcn_mfma_f32_16x16x32_f16(A[0][1], B, CB[0][1], 0, 0, 0);
        d0 = lrelu4(d0); d1 = lrelu4(d1);
        f32x4 e1lo = d0, e1hi = d1;              // skip connection (f32)

        // conv2
        B = xchg(d0, d1, a01, a23, hiq);
        d0 = __builtin_amdgcn_mfma_f32_16x16x32_f16(A[1][0], B, CB[1][0], 0, 0, 0);
        d1 = __builtin_amdgcn_mfma_f32_16x16x32_f16(A[1][1], B, CB[1][1], 0, 0, 0);
        d0 = lrelu4(d0); d1 = lrelu4(d1);

        // conv3 (+ skip)
        B = xchg(d0, d1, a01, a23, hiq);
        d0 = __builtin_amdgcn_mfma_f32_16x16x32_f16(A[2][0], B, CB[2][0], 0, 0, 0);
        d1 = __builtin_amdgcn_mfma_f32_16x16x32_f16(A[2][1], B, CB[2][1], 0, 0, 0);
        d0 = lrelu4(d0) + e1lo; d1 = lrelu4(d1) + e1hi;

        // conv4 + tanh
        B = xchg(d0, d1, a01, a23, hiq);
        d0 = __builtin_amdgcn_mfma_f32_16x16x32_f16(A[3][0], B, CB[3][0], 0, 0, 0);
        d1 = __builtin_amdgcn_mfma_f32_16x16x32_f16(A[3][1], B, CB[3][1], 0, 0, 0);
        f32x4 o0 = { fast_tanh(d0.x), fast_tanh(d0.y),
                     fast_tanh(d0.z), fast_tanh(d0.w) };
        f32x4 o1 = { fast_tanh(d1.x), fast_tanh(d1.y),
                     fast_tanh(d1.z), fast_tanh(d1.w) };

        // D rows (oc*16+l) == output word index: write straight to own row
        *(f32x4*)(xrow + 4 * q)      = o0;       // rows 4q..4q+3
        *(f32x4*)(xrow + 16 + 4 * q) = o1;       // rows 16+4q..16+4q+3
    }
    __syncthreads();

    // ---- stage out: LDS -> coalesced global ----
    float4* outp = (float4*)out;
#pragma unroll
    for (int qq = 0; qq < 8; ++qq) {
        int g = qq * 256 + t;
        outp[blockBase + g] = s4[(g >> 3) * 9 + (g & 7)];
    }
}

extern "C" void kernel_launch(void* const* d_in, const int* in_sizes, int n_in,
                              void* d_out, int out_size, void* d_ws, size_t ws_size,
                              hipStream_t stream) {
    const float* x  = (const float*)d_in[0];
    const float* w1 = (const float*)d_in[1];
    const float* b1 = (const float*)d_in[2];
    const float* w2 = (const float*)d_in[3];
    const float* b2 = (const float*)d_in[4];
    const float* w3 = (const float*)d_in[5];
    const float* b3 = (const float*)d_in[6];
    const float* w4 = (const float*)d_in[7];
    const float* b4 = (const float*)d_in[8];
    float* out = (float*)d_out;

    int n = in_sizes[0] / 32;            // B = 262144 samples, 256 per block
    int grid = n / 256;                  // 1024 blocks, exact
    hipLaunchKernelGGL(minigen_kernel, dim3(grid), dim3(256), 0, stream,
                       x, w1, b1, w2, b2, w3, b3, w4, b4, out);
}

// Round 9
// 106.074 us; speedup vs baseline: 1.0609x; 1.0609x over previous
//
#include <hip/hip_runtime.h>

#define SLOPE 0.2f

__device__ __forceinline__ float leaky(float v) {
    return __builtin_fmaxf(v, SLOPE * v);
}
__device__ __forceinline__ float fast_tanh(float v) {
    float e = __expf(2.0f * v);
    return 1.0f - 2.0f * __builtin_amdgcn_rcpf(e + 1.0f);
}

// Quad-lane shifts via DPP quad_perm; the 4 lanes of a quad are the 4
// threads of one sample. MUST run under full EXEC (R4 lesson): compute
// unconditionally, select (cndmask) after.
__device__ __forceinline__ float qprev(float v) {   // from lane p-1 (sel [3,0,1,2])
    int i = __builtin_bit_cast(int, v);
    i = __builtin_amdgcn_mov_dpp(i, 0x93, 0xF, 0xF, true);
    return __builtin_bit_cast(float, i);
}
__device__ __forceinline__ float qnext(float v) {   // from lane p+1 (sel [1,2,3,0])
    int i = __builtin_bit_cast(int, v);
    i = __builtin_amdgcn_mov_dpp(i, 0x39, 0xF, 0xF, true);
    return __builtin_bit_cast(float, i);
}

// R9 theory: the ~28us plateau across four different compute engines was
// never compute -- it was block-level pipelining (R1: OccupancyPercent 16%,
// ~5 waves/CU resident vs 16 cap; 1024 fat blocks with barrier-serialized
// phases). This kernel: 4 threads/sample, 64 samples/block -> 4096 blocks,
// 9 KB LDS, VGPR<=64 via (256,8) -> 8 blocks/CU RESIDENT (32 waves/CU),
// 4x shorter phases, deep cross-block overlap of load/compute/store.
__global__ __launch_bounds__(256, 8) void minigen_kernel(
    const float* __restrict__ x,
    const float* __restrict__ w1, const float* __restrict__ b1,
    const float* __restrict__ w2, const float* __restrict__ b2,
    const float* __restrict__ w3, const float* __restrict__ b3,
    const float* __restrict__ w4, const float* __restrict__ b4,
    float* __restrict__ out)
{
    __shared__ float4 lds[64 * 9];            // 64 samples x (8 f4 + pad) = 9 KB

    const int t = threadIdx.x;
    const int p = t & 3;                       // quarter of the sample
    const int sb = t >> 2;                     // sample row in LDS
    const int base = blockIdx.x * 512;         // f4 units (512 f4 per block)

    // ---- stage in: coalesced global -> LDS ----
    const float4* xin = (const float4*)x;
    lds[(t >> 3) * 9 + (t & 7)] = xin[base + t];
    {
        int g = 256 + t;
        lds[(g >> 3) * 9 + (g & 7)] = xin[base + g];
    }
    __syncthreads();

    // ---- own quarter: x[ic][4p + j], j=0..3 ----
    float xr[2][4];
#pragma unroll
    for (int ic = 0; ic < 2; ++ic) {
        float4 v = lds[sb * 9 + ic * 4 + p];
        xr[ic][0] = v.x; xr[ic][1] = v.y; xr[ic][2] = v.z; xr[ic][3] = v.w;
    }

    // ---- conv1: [2,16] -> [4,8], s2 p1, leaky; own cols l=2p,2p+1 ----
    float xh[2];
#pragma unroll
    for (int ic = 0; ic < 2; ++ic) {
        float h = qprev(xr[ic][3]);            // x[ic][4p-1]
        xh[ic] = p ? h : 0.0f;                 // p==0: left pad
    }
    float e1q[4][2];                           // e1[oc][2p+dl]
#pragma unroll
    for (int oc = 0; oc < 4; ++oc) {
#pragma unroll
        for (int dl = 0; dl < 2; ++dl) {
            float s = b1[oc];
#pragma unroll
            for (int ic = 0; ic < 2; ++ic)
#pragma unroll
                for (int k = 0; k < 3; ++k) {
                    int u = 2 * dl - 1 + k;    // [-1..3] compile-time
                    float v = (u < 0) ? xh[ic] : xr[ic][u];
                    s = fmaf(v, w1[(oc * 2 + ic) * 3 + k], s);
                }
            e1q[oc][dl] = leaky(s);
        }
    }

    // ---- conv2: [4,8] -> [8,4], s2 p1, leaky; own col = p ----
    float eh[4];
#pragma unroll
    for (int ic = 0; ic < 4; ++ic) {
        float h = qprev(e1q[ic][1]);           // e1[ic][2p-1]
        eh[ic] = p ? h : 0.0f;
    }
    float bn[8];                               // bn[oc][p]
#pragma unroll
    for (int oc = 0; oc < 8; ++oc) {
        float s = b2[oc];
#pragma unroll
        for (int ic = 0; ic < 4; ++ic) {
            s = fmaf(eh[ic],      w2[(oc * 4 + ic) * 3 + 0], s);
            s = fmaf(e1q[ic][0],  w2[(oc * 4 + ic) * 3 + 1], s);
            s = fmaf(e1q[ic][1],  w2[(oc * 4 + ic) * 3 + 2], s);
        }
        bn[oc] = leaky(s);
    }

    // ---- up1(x2) + conv3: [8,8] -> [4,8], s1 p1, leaky, +skip e1 ----
    // own cols l=2p,2p+1; up1[u]=bn[u>>1]; halos bn[p-1] (left), bn[p+1] (right)
    float bl[8], br[8];
#pragma unroll
    for (int ic = 0; ic < 8; ++ic) {
        float hl = qprev(bn[ic]);
        float hr = qnext(bn[ic]);
        bl[ic] = p ? hl : 0.0f;                // p==0: u=-1 pad
        br[ic] = (p == 3) ? 0.0f : hr;         // p==3: u=8 pad
    }
    float skq[4][2];                           // sk[oc][2p+dl]
#pragma unroll
    for (int oc = 0; oc < 4; ++oc) {
        // dl=0: taps u=2p-1,2p,2p+1 -> bl, bn, bn
        float s0 = b3[oc];
        // dl=1: taps u=2p,2p+1,2p+2 -> bn, bn, br
        float s1 = b3[oc];
#pragma unroll
        for (int ic = 0; ic < 8; ++ic) {
            const float* wr = w3 + (oc * 8 + ic) * 3;
            s0 = fmaf(bl[ic], wr[0], s0);
            s0 = fmaf(bn[ic], wr[1], s0);
            s0 = fmaf(bn[ic], wr[2], s0);
            s1 = fmaf(bn[ic], wr[0], s1);
            s1 = fmaf(bn[ic], wr[1], s1);
            s1 = fmaf(br[ic], wr[2], s1);
        }
        skq[oc][0] = leaky(s0) + e1q[oc][0];
        skq[oc][1] = leaky(s1) + e1q[oc][1];
    }

    // ---- up2(x2) + conv4: [4,16] -> [2,16], s1 p1, tanh ----
    // own cols l=4p..4p+3; up2[u]=sk[u>>1]; halos sk[2p-1] (left), sk[2p+2] (right)
    float sl[4], sr[4];
#pragma unroll
    for (int ic = 0; ic < 4; ++ic) {
        float hl = qprev(skq[ic][1]);          // sk[ic][2p-1]
        float hr = qnext(skq[ic][0]);          // sk[ic][2p+2]
        sl[ic] = p ? hl : 0.0f;
        sr[ic] = (p == 3) ? 0.0f : hr;
    }
    float o[2][4];
#pragma unroll
    for (int oc = 0; oc < 2; ++oc) {
        float a0 = b4[oc], a1 = b4[oc], a2 = b4[oc], a3 = b4[oc];
#pragma unroll
        for (int ic = 0; ic < 4; ++ic) {
            const float* wr = w4 + (oc * 4 + ic) * 3;
            float s0 = skq[ic][0], s1 = skq[ic][1];
            // dl=0: u=4p-1,4p,4p+1 -> sl, s0, s0
            a0 = fmaf(sl[ic], wr[0], a0);
            a0 = fmaf(s0,     wr[1], a0);
            a0 = fmaf(s0,     wr[2], a0);
            // dl=1: u=4p,4p+1,4p+2 -> s0, s0, s1
            a1 = fmaf(s0,     wr[0], a1);
            a1 = fmaf(s0,     wr[1], a1);
            a1 = fmaf(s1,     wr[2], a1);
            // dl=2: u=4p+1..4p+3 -> s0, s1, s1
            a2 = fmaf(s0,     wr[0], a2);
            a2 = fmaf(s1,     wr[1], a2);
            a2 = fmaf(s1,     wr[2], a2);
            // dl=3: u=4p+2..4p+4 -> s1, s1, sr
            a3 = fmaf(s1,     wr[0], a3);
            a3 = fmaf(s1,     wr[1], a3);
            a3 = fmaf(sr[ic], wr[2], a3);
        }
        o[oc][0] = fast_tanh(a0); o[oc][1] = fast_tanh(a1);
        o[oc][2] = fast_tanh(a2); o[oc][3] = fast_tanh(a3);
    }

    // ---- own slots back to LDS (same slots this thread read) ----
#pragma unroll
    for (int oc = 0; oc < 2; ++oc)
        lds[sb * 9 + oc * 4 + p] =
            make_float4(o[oc][0], o[oc][1], o[oc][2], o[oc][3]);
    __syncthreads();

    // ---- stage out: LDS -> coalesced global ----
    float4* outp = (float4*)out;
    outp[base + t] = lds[(t >> 3) * 9 + (t & 7)];
    {
        int g = 256 + t;
        outp[base + g] = lds[(g >> 3) * 9 + (g & 7)];
    }
}

extern "C" void kernel_launch(void* const* d_in, const int* in_sizes, int n_in,
                              void* d_out, int out_size, void* d_ws, size_t ws_size,
                              hipStream_t stream) {
    const float* x  = (const float*)d_in[0];
    const float* w1 = (const float*)d_in[1];
    const float* b1 = (const float*)d_in[2];
    const float* w2 = (const float*)d_in[3];
    const float* b2 = (const float*)d_in[4];
    const float* w3 = (const float*)d_in[5];
    const float* b3 = (const float*)d_in[6];
    const float* w4 = (const float*)d_in[7];
    const float* b4 = (const float*)d_in[8];
    float* out = (float*)d_out;

    int n = in_sizes[0] / 32;            // B = 262144 samples, 64 per block
    int grid = n / 64;                   // 4096 blocks, exact
    hipLaunchKernelGGL(minigen_kernel, dim3(grid), dim3(256), 0, stream,
                       x, w1, b1, w2, b2, w3, b3, w4, b4, out);
}